// Round 1
// baseline (183.684 us; speedup 1.0000x reference)
//
#include <hip/hip_runtime.h>

namespace {
constexpr int S = 1024;
constexpr int H = 512;
constexpr int W = 512;
constexpr int B = 32;
constexpr int OFF = 256; // (S-H)/2 = (S-W)/2

__device__ __forceinline__ int refl(int i) {
    // jnp.mod(i, 2S) with 2S=2048 (pow2): bitmask gives the nonneg residue.
    int m = i & (2 * S - 1);
    return (m < S) ? m : (2 * S - 1 - m);
}

__device__ __forceinline__ bool stripe(int i, int start, int gb, int len, int n, float inv_gb) {
    int d = i - start;
    if (d < 0) return false;
    // exact integer div by runtime gb: float estimate + one-step fixup
    int q = (int)((float)d * inv_gb);
    int r = d - q * gb;
    if (r < 0)        { r += gb; --q; }
    else if (r >= gb) { r -= gb; ++q; }
    return (r < len) && (q < n);
}

__global__ __launch_bounds__(256) void gridmask_kernel(
    const float* __restrict__ images,
    const float* __restrict__ angles,
    const int* __restrict__ gridblock,
    const int* __restrict__ start1,
    const int* __restrict__ start2,
    float* __restrict__ out)
{
    const int t   = blockIdx.x * 256 + threadIdx.x; // one thread = 4 px
    const int b   = t >> 16;        // H*W/4 = 65536 groups per image
    const int rem = t & 65535;
    const int y   = rem >> 7;       // W/4 = 128 groups per row
    const int x   = (rem & 127) << 2;

    const float ang = angles[b];
    const int gb = gridblock[b];
    const int s1 = start1[b];
    const int s2 = start2[b];

    const float gbf = (float)gb;
    // match numpy's two-step f32 rounding exactly: no FMA contraction
    int len = (int)(__fadd_rn(__fmul_rn(gbf, 0.6f), 0.5f));
    len = min(max(len, 1), gb - 1);
    const int n = S / gb;
    const float inv_gb = 1.0f / gbf;

    float sn, cs;
    sincosf(ang, &sn, &cs);

    const float c = (float)(S - 1) * 0.5f; // 511.5
    const float Y = (float)(y + OFF) - c;

    const size_t base = (size_t)t * 12;    // 4 px * 3 ch, 48B -> 16B aligned
    const float4* ip = (const float4*)(images + base);
    const float4 p0 = ip[0];
    const float4 p1 = ip[1];
    const float4 p2 = ip[2];

    float m[4];
#pragma unroll
    for (int i = 0; i < 4; ++i) {
        const float X  = (float)(x + i + OFF) - c;
        const float sx =  cs * X + sn * Y + c;
        const float sy =  cs * Y - sn * X + c;
        const float x0f = floorf(sx);
        const float y0f = floorf(sy);
        const float fx = sx - x0f;
        const float fy = sy - y0f;
        const int x0i = (int)x0f;
        const int y0i = (int)y0f;
        const int x0r = refl(x0i), x1r = refl(x0i + 1);
        const int y0r = refl(y0i), y1r = refl(y0i + 1);
        const bool c0 = stripe(x0r, s2, gb, len, n, inv_gb);
        const bool c1 = stripe(x1r, s2, gb, len, n, inv_gb);
        const bool r0 = stripe(y0r, s1, gb, len, n, inv_gb);
        const bool r1 = stripe(y1r, s1, gb, len, n, inv_gb);
        const float v00 = (r0 | c0) ? 1.0f : 0.0f;
        const float v01 = (r0 | c1) ? 1.0f : 0.0f;
        const float v10 = (r1 | c0) ? 1.0f : 0.0f;
        const float v11 = (r1 | c1) ? 1.0f : 0.0f;
        m[i] = (v00 * (1.0f - fx) + v01 * fx) * (1.0f - fy)
             + (v10 * (1.0f - fx) + v11 * fx) * fy;
    }

    float4 o0, o1, o2;
    o0.x = p0.x * m[0]; o0.y = p0.y * m[0]; o0.z = p0.z * m[0]; o0.w = p0.w * m[1];
    o1.x = p1.x * m[1]; o1.y = p1.y * m[1]; o1.z = p1.z * m[2]; o1.w = p1.w * m[2];
    o2.x = p2.x * m[2]; o2.y = p2.y * m[3]; o2.z = p2.z * m[3]; o2.w = p2.w * m[3];

    float4* op = (float4*)(out + base);
    op[0] = o0; op[1] = o1; op[2] = o2;
}
} // namespace

extern "C" void kernel_launch(void* const* d_in, const int* in_sizes, int n_in,
                              void* d_out, int out_size, void* d_ws, size_t ws_size,
                              hipStream_t stream) {
    const float* images    = (const float*)d_in[0];
    const float* angles    = (const float*)d_in[1];
    const int*   gridblock = (const int*)d_in[2];
    const int*   start1    = (const int*)d_in[3];
    const int*   start2    = (const int*)d_in[4];
    float* outp = (float*)d_out;

    const int total_groups = B * H * W / 4; // 2,097,152 threads
    const int blocks = total_groups / 256;  // 8192 blocks
    gridmask_kernel<<<blocks, 256, 0, stream>>>(images, angles, gridblock, start1, start2, outp);
}

// Round 2
// 181.742 us; speedup vs baseline: 1.0107x; 1.0107x over previous
//
#include <hip/hip_runtime.h>

namespace {
constexpr int S = 1024;
constexpr int H = 512;
constexpr int W = 512;
constexpr int B = 32;
constexpr int OFF = 256; // (S-H)/2 = (S-W)/2

__device__ __forceinline__ int refl(int i) {
    // jnp.mod(i, 2S) with 2S=2048 (pow2): bitmask gives the nonneg residue.
    int m = i & (2 * S - 1);
    return (m < S) ? m : (2 * S - 1 - m);
}

__device__ __forceinline__ bool stripe(int i, int start, int gb, int len, int n, float inv_gb) {
    int d = i - start;
    if (d < 0) return false;
    // exact integer div by runtime gb: float estimate + one-step fixup
    int q = (int)((float)d * inv_gb);
    int r = d - q * gb;
    if (r < 0)        { r += gb; --q; }
    else if (r >= gb) { r -= gb; ++q; }
    return (r < len) && (q < n);
}

__global__ __launch_bounds__(256) void gridmask_kernel(
    const float* __restrict__ images,
    const float* __restrict__ angles,
    const int* __restrict__ gridblock,
    const int* __restrict__ start1,
    const int* __restrict__ start2,
    float* __restrict__ out)
{
    __shared__ float mlds[1024];

    const int tid = threadIdx.x;
    const int blk = blockIdx.x;          // 8192 blocks, 256 per image
    const int b   = blk >> 8;            // wave-uniform batch index
    const int pix_base = (blk & 255) << 10; // local pixel base within image

    // ---------------- Phase 1: masks for 4 pixels -> LDS ----------------
    {
        const int p0   = tid << 2;           // local pixel [0,1024)
        const int gpix = pix_base + p0;      // pixel within image
        const int y    = gpix >> 9;          // row [0,512)
        const int x    = gpix & 511;         // col, multiple of 4

        const float ang = angles[b];
        const int gb = gridblock[b];
        const int s1 = start1[b];
        const int s2 = start2[b];

        const float gbf = (float)gb;
        // match numpy's two-step f32 rounding exactly: no FMA contraction
        int len = (int)(__fadd_rn(__fmul_rn(gbf, 0.6f), 0.5f));
        len = min(max(len, 1), gb - 1);
        const int n = S / gb;
        const float inv_gb = 1.0f / gbf;

        float sn, cs;
        sincosf(ang, &sn, &cs);

        const float c = (float)(S - 1) * 0.5f; // 511.5
        const float Y = (float)(y + OFF) - c;

        float m[4];
#pragma unroll
        for (int i = 0; i < 4; ++i) {
            const float X  = (float)(x + i + OFF) - c;
            const float sx =  cs * X + sn * Y + c;
            const float sy =  cs * Y - sn * X + c;
            const float x0f = floorf(sx);
            const float y0f = floorf(sy);
            const float fx = sx - x0f;
            const float fy = sy - y0f;
            const int x0i = (int)x0f;
            const int y0i = (int)y0f;
            const int x0r = refl(x0i), x1r = refl(x0i + 1);
            const int y0r = refl(y0i), y1r = refl(y0i + 1);
            const bool c0 = stripe(x0r, s2, gb, len, n, inv_gb);
            const bool c1 = stripe(x1r, s2, gb, len, n, inv_gb);
            const bool r0 = stripe(y0r, s1, gb, len, n, inv_gb);
            const bool r1 = stripe(y1r, s1, gb, len, n, inv_gb);
            const float v00 = (r0 | c0) ? 1.0f : 0.0f;
            const float v01 = (r0 | c1) ? 1.0f : 0.0f;
            const float v10 = (r1 | c0) ? 1.0f : 0.0f;
            const float v11 = (r1 | c1) ? 1.0f : 0.0f;
            m[i] = (v00 * (1.0f - fx) + v01 * fx) * (1.0f - fy)
                 + (v10 * (1.0f - fx) + v11 * fx) * fy;
        }
        float4* ml4 = (float4*)mlds;
        ml4[tid] = make_float4(m[0], m[1], m[2], m[3]);
    }
    __syncthreads();

    // ---------------- Phase 2: fully coalesced multiply sweep ----------------
    const size_t fbase = (size_t)blk * 3072;  // block's float base
    const float4* __restrict__ gin4  = (const float4*)(images + fbase);
    float4* __restrict__       gout4 = (float4*)(out + fbase);

    // issue all 3 loads up front for ILP
    const float4 p0 = gin4[tid];
    const float4 p1 = gin4[tid + 256];
    const float4 p2 = gin4[tid + 512];

#pragma unroll
    for (int j = 0; j < 3; ++j) {
        const int lf = (j << 10) + (tid << 2);   // local float index [0,3072)
        const int q  = lf / 3;                   // pixel of first component
        const int r  = lf - q * 3;
        const float ma = mlds[q];
        const float mb = mlds[q + 1 <= 1023 ? q + 1 : 1023];
        // component c belongs to pixel q + ((r+c) >= 3)
        const float m0 = (r + 0 >= 3) ? mb : ma;
        const float m1 = (r + 1 >= 3) ? mb : ma;
        const float m2 = (r + 2 >= 3) ? mb : ma;
        const float m3 = (r + 3 >= 3) ? mb : ma;
        const float4 p = (j == 0) ? p0 : (j == 1) ? p1 : p2;
        float4 o;
        o.x = p.x * m0;
        o.y = p.y * m1;
        o.z = p.z * m2;
        o.w = p.w * m3;
        gout4[(j << 8) + tid] = o;
    }
}
} // namespace

extern "C" void kernel_launch(void* const* d_in, const int* in_sizes, int n_in,
                              void* d_out, int out_size, void* d_ws, size_t ws_size,
                              hipStream_t stream) {
    const float* images    = (const float*)d_in[0];
    const float* angles    = (const float*)d_in[1];
    const int*   gridblock = (const int*)d_in[2];
    const int*   start1    = (const int*)d_in[3];
    const int*   start2    = (const int*)d_in[4];
    float* outp = (float*)d_out;

    const int blocks = B * H * W / 1024; // 8192 blocks x 256 threads, 4 px/thread
    gridmask_kernel<<<blocks, 256, 0, stream>>>(images, angles, gridblock, start1, start2, outp);
}